// Round 7
// baseline (304.870 us; speedup 1.0000x reference)
//
#include <hip/hip_runtime.h>
#include <math.h>

#define NNODES 50000
#define NEDGES 800000
#define ETOT   850000      // NEDGES + NNODES self-loops
#define SLOPE  0.2f
#define BSLOTS 96          // bucket slots/node; P(Poisson(17) deg >= 96) < 1e-40
#define CPAD   16          // cnt stride: one counter per 64B line (atomic false-sharing fix)
#define NTILE  782         // ceil(NNODES/64) gemm1 tiles
#define BBLK   518         // bucket blocks appended after the gemm tiles

typedef unsigned short ushort_t;
typedef unsigned int   uint_t;
typedef unsigned char  uchar_t;
typedef __attribute__((ext_vector_type(8))) __bf16 bf16x8;
typedef __attribute__((ext_vector_type(4))) float  floatx4;
typedef __attribute__((ext_vector_type(2))) float  floatx2;

// gfx950 has HW OCP-e4m3 <-> f32 converters (v_cvt_pk_f32_fp8 / v_cvt_pk_fp8_f32).
#if defined(__has_builtin)
#if __has_builtin(__builtin_amdgcn_cvt_pk_f32_fp8) && __has_builtin(__builtin_amdgcn_cvt_pk_fp8_f32)
#define HWFP8 1
#endif
#endif

__device__ __forceinline__ float leaky(float v) { return fmaxf(v, SLOPE * v); }  // slope<1

__device__ __forceinline__ ushort_t f2bf(float f) {       // fp32 -> bf16 RNE
    uint_t u = __float_as_uint(f);
    uint_t r = (u + 0x7fffu + ((u >> 16) & 1u)) >> 16;
    return (ushort_t)r;
}

// ---- software fallback fp8 codec (only compiled if HW builtins are absent) ----
__device__ __forceinline__ uint_t f2fp8_sw(float f) {
    uint_t u = __float_as_uint(f);
    uint_t s = (u >> 24) & 0x80u;
    u &= 0x7fffffffu;
    u = u + 0x7ffffu + ((u >> 20) & 1u);      // RNE to 3 mantissa bits
    int e8 = (int)(u >> 23) - 120;            // fp32 bias 127 -> e4m3 bias 7
    uint_t m3 = (u >> 20) & 7u;
    if (e8 <= 0) return s;                    // flush denormal / zero
    if (e8 >= 16) return s | 0x7eu;           // saturate to 448
    return s | ((uint_t)e8 << 3) | m3;
}
__device__ __forceinline__ float fp8tof_sw(uint_t b) {
    uint_t t = (b & 0x7fu) << 4;
    uint_t r = ((b & 0x80u) << 8) | (t + 0x3C00u);
    return (t >= 0x80u) ? __uint_as_float(r << 16) : 0.f;
}

// pack 4 f32 -> 4 e4m3 bytes (byte c = channel c)
__device__ __forceinline__ uint_t pk4fp8(float a, float b, float c, float d) {
#ifdef HWFP8
    int pk = 0;
    pk = __builtin_amdgcn_cvt_pk_fp8_f32(a, b, pk, false);   // bytes 0,1
    pk = __builtin_amdgcn_cvt_pk_fp8_f32(c, d, pk, true);    // bytes 2,3
    return (uint_t)pk;
#else
    return f2fp8_sw(a) | (f2fp8_sw(b) << 8) | (f2fp8_sw(c) << 16) | (f2fp8_sw(d) << 24);
#endif
}

// decode 16 e4m3 bytes (uint4) and accumulate: acc[c] += w * val[c], c = 0..15
__device__ __forceinline__ void dec16acc(uint4 v, float w, float* acc) {
#ifdef HWFP8
    floatx2 f;
    f = __builtin_amdgcn_cvt_pk_f32_fp8((int)v.x, false); acc[0]  += w * f.x; acc[1]  += w * f.y;
    f = __builtin_amdgcn_cvt_pk_f32_fp8((int)v.x, true);  acc[2]  += w * f.x; acc[3]  += w * f.y;
    f = __builtin_amdgcn_cvt_pk_f32_fp8((int)v.y, false); acc[4]  += w * f.x; acc[5]  += w * f.y;
    f = __builtin_amdgcn_cvt_pk_f32_fp8((int)v.y, true);  acc[6]  += w * f.x; acc[7]  += w * f.y;
    f = __builtin_amdgcn_cvt_pk_f32_fp8((int)v.z, false); acc[8]  += w * f.x; acc[9]  += w * f.y;
    f = __builtin_amdgcn_cvt_pk_f32_fp8((int)v.z, true);  acc[10] += w * f.x; acc[11] += w * f.y;
    f = __builtin_amdgcn_cvt_pk_f32_fp8((int)v.w, false); acc[12] += w * f.x; acc[13] += w * f.y;
    f = __builtin_amdgcn_cvt_pk_f32_fp8((int)v.w, true);  acc[14] += w * f.x; acc[15] += w * f.y;
#else
    uint_t ws[4] = {v.x, v.y, v.z, v.w};
    #pragma unroll
    for (int q = 0; q < 4; ++q) {
        acc[q*4+0] += w * fp8tof_sw(ws[q] & 0xffu);
        acc[q*4+1] += w * fp8tof_sw((ws[q] >> 8) & 0xffu);
        acc[q*4+2] += w * fp8tof_sw((ws[q] >> 16) & 0xffu);
        acc[q*4+3] += w * fp8tof_sw(ws[q] >> 24);
    }
#endif
}

__device__ __forceinline__ float hsel(float4 v, int h) {  // v[h]
    float t0 = (h & 1) ? v.y : v.x;
    float t1 = (h & 1) ? v.w : v.z;
    return (h & 2) ? t1 : t0;
}

__device__ __forceinline__ int esrc(const int* ei, int e) { return e < NEDGES ? ei[e]          : e - NEDGES; }
__device__ __forceinline__ int edst(const int* ei, int e) { return e < NEDGES ? ei[NEDGES + e] : e - NEDGES; }

// ------- prep: W1->bf16 chunk conv + b1/W2 permute + padded-cnt zero (one kernel) -------
__global__ void prep_k(const float* __restrict__ W1, ushort_t* __restrict__ W1c,
                       const float* __restrict__ b1, const float* __restrict__ W2,
                       float* __restrict__ b1p, float* __restrict__ W2p,
                       int* __restrict__ cnt) {
    int bid = blockIdx.x, tid = threadIdx.x;
    int gtid = bid * 256 + tid;
    if (bid < 256) {                          // W1 row-major [k][n] -> W1c[kc][n][kk]
        int k = gtid >> 8, n = gtid & 255;
        W1c[(k >> 5) * 8192 + n * 32 + (k & 31)] = f2bf(W1[gtid]);
    } else if (bid == 256) {                  // permuted channel: head*64 + c15*4 + tn
        int chp = tid;
        int q = chp & 63, cc = q >> 2, t = q & 3;
        int ch = (chp & 192) | (t * 16 + cc);
        b1p[chp] = b1[ch];
        #pragma unroll
        for (int j = 0; j < 8; ++j) W2p[chp * 8 + j] = W2[ch * 8 + j];
    }
    for (int i = gtid; i < NNODES * CPAD; i += 257 * 256) cnt[i] = 0;
}

// ------- fused gemm1 || bucket: blocks [0,NTILE) do MFMA tiles, rest bucket edges -------
__global__ __launch_bounds__(256) void gb_k(const float* __restrict__ X,
                                            const ushort_t* __restrict__ W1c,
                                            const float* __restrict__ att_s,
                                            const float* __restrict__ att_d,
                                            uchar_t* __restrict__ h1f,
                                            float* __restrict__ as1,
                                            float* __restrict__ ad1,
                                            const int* __restrict__ ei,
                                            int* __restrict__ cnt,
                                            int* __restrict__ bkt) {
    __shared__ ushort_t Als[64 * 40];     // A tile [64][32] bf16, row pad to 40
    __shared__ ushort_t Bls[256 * 40];    // Bt tile [256 n][32 k] bf16, row pad to 40
    int tid = threadIdx.x;

    if (blockIdx.x >= NTILE) {
        // -------- bucketed CSR over the edge list (+ implicit self-loops) --------
        for (int e = (blockIdx.x - NTILE) * 256 + tid; e < ETOT; e += BBLK * 256) {
            int d = edst(ei, e), s = esrc(ei, e);
            int pos = atomicAdd(&cnt[d * CPAD], 1);
            if (pos < BSLOTS) bkt[d * BSLOTS + pos] = s;
        }
        return;
    }

    // -------- one 64-row gemm tile --------
    int row0 = blockIdx.x * 64;
    int wv = tid >> 6, lane = tid & 63, c15 = lane & 15, quad = lane >> 4;
    floatx4 acc[4][4] = {};               // [tm][tn]

    for (int kc = 0; kc < 8; ++kc) {
        __syncthreads();
        {
            int r = tid >> 3, c4 = tid & 7;
            #pragma unroll
            for (int p = 0; p < 2; ++p) {
                int rr = r + p * 32;
                int row = row0 + rr;
                float4 v = make_float4(0.f, 0.f, 0.f, 0.f);
                if (row < NNODES) v = *(const float4*)&X[(size_t)row * 256 + kc * 32 + c4 * 4];
                uint2 pk;
                pk.x = (uint_t)f2bf(v.x) | ((uint_t)f2bf(v.y) << 16);
                pk.y = (uint_t)f2bf(v.z) | ((uint_t)f2bf(v.w) << 16);
                *(uint2*)&Als[rr * 40 + c4 * 4] = pk;
            }
        }
        {
            const uint4* srcp = (const uint4*)(W1c + kc * 8192);
            #pragma unroll
            for (int c = 0; c < 4; ++c) {
                int el = tid + c * 256;          // uint4 index, 1024 total
                uint4 v = srcp[el];
                int n = el >> 2, kk8 = (el & 3) * 8;
                *(uint4*)&Bls[n * 40 + kk8] = v;
            }
        }
        __syncthreads();
        uint4 af[4], bfr[4];
        #pragma unroll
        for (int t = 0; t < 4; ++t)
            af[t] = *(const uint4*)&Als[(t * 16 + c15) * 40 + quad * 8];
        #pragma unroll
        for (int t = 0; t < 4; ++t)
            bfr[t] = *(const uint4*)&Bls[(wv * 64 + t * 16 + c15) * 40 + quad * 8];
        #pragma unroll
        for (int tm = 0; tm < 4; ++tm)
            #pragma unroll
            for (int tn = 0; tn < 4; ++tn)
                acc[tm][tn] = __builtin_amdgcn_mfma_f32_16x16x32_bf16(
                    __builtin_bit_cast(bf16x8, af[tm]),
                    __builtin_bit_cast(bf16x8, bfr[tn]),
                    acc[tm][tn], 0, 0, 0);
    }

    // alpha partials on ORIGINAL channel indexing (heads unchanged by the permute)
    // NOTE: computed from fp32 acc BEFORE fp8 quantization -> logits stay accurate
    float asv[4], adv[4];
    #pragma unroll
    for (int tn = 0; tn < 4; ++tn) {
        asv[tn] = att_s[wv * 64 + tn * 16 + c15];
        adv[tn] = att_d[wv * 64 + tn * 16 + c15];
    }
    float ps[4][4], pd[4][4];
    #pragma unroll
    for (int tm = 0; tm < 4; ++tm)
        #pragma unroll
        for (int r = 0; r < 4; ++r) {
            float vs = 0.f, vd = 0.f;
            #pragma unroll
            for (int tn = 0; tn < 4; ++tn) {
                float a = acc[tm][tn][r];
                vs += a * asv[tn]; vd += a * adv[tn];
            }
            ps[tm][r] = vs; pd[tm][r] = vd;
        }
    // permuted fp8 stores: h1f[row][wv*64 + c15*4 + tn] -> one uint (4 e4m3) per (tm,r)
    #pragma unroll
    for (int tm = 0; tm < 4; ++tm) {
        #pragma unroll
        for (int r = 0; r < 4; ++r) {
            int row = row0 + tm * 16 + quad * 4 + r;
            if (row < NNODES) {
                uint_t pk = pk4fp8(acc[tm][0][r], acc[tm][1][r],
                                   acc[tm][2][r], acc[tm][3][r]);
                *(uint_t*)&h1f[(size_t)row * 256 + wv * 64 + c15 * 4] = pk;
            }
        }
    }
    #pragma unroll
    for (int off = 1; off < 16; off <<= 1)
        #pragma unroll
        for (int tm = 0; tm < 4; ++tm)
            #pragma unroll
            for (int r = 0; r < 4; ++r) {
                ps[tm][r] += __shfl_xor(ps[tm][r], off, 64);
                pd[tm][r] += __shfl_xor(pd[tm][r], off, 64);
            }
    if (c15 == 0) {
        #pragma unroll
        for (int tm = 0; tm < 4; ++tm)
            #pragma unroll
            for (int r = 0; r < 4; ++r) {
                int row = row0 + tm * 16 + quad * 4 + r;
                if (row < NNODES) {
                    as1[row * 4 + wv] = ps[tm][r];
                    ad1[row * 4 + wv] = pd[tm][r];
                }
            }
    }
}

// ------- fused layer-1: TWO nodes per wave, quarter-group uint4 gather (r5 schedule) -------
// r5 front-end/order preserved (measured best: 85 us, VGPR 52). Only the load geometry
// changed: each 16-lane quarter-group covers one full 256 B fp8 row (16 B/lane uint4),
// so ONE wave-instruction serves 4 edges (2 per node) instead of 2 -> load-instruction
// count halves. Lane owns 16 channels of edges with parity g=(l32>>4); a single
// shfl_xor(16) add merges the two parity accumulators at the end.
#define PREL(BASE, VV)                                                          \
    {                                                                           \
        _Pragma("unroll")                                                       \
        for (int j = 0; j < 4; ++j) {                                           \
            int e = (BASE) + 2 * j + g;                                         \
            int se = __shfl(s_reg, sbase + e, 64);                              \
            if (e < deg)                                                        \
                VV[j] = *(const uint4*)&h1f[(size_t)se * 256 + koff];           \
        }                                                                       \
    }
#define PREW(BASE, WW)                                                          \
    {                                                                           \
        _Pragma("unroll")                                                       \
        for (int j = 0; j < 4; ++j) WW[j] = wls[wv][half][(BASE) + 2*j + g][h]; \
    }
#define CONS(BASE, VV, WW)                                                      \
    {                                                                           \
        _Pragma("unroll")                                                       \
        for (int j = 0; j < 4; ++j) {                                           \
            if ((BASE) + 2 * j + g < deg) dec16acc(VV[j], WW[j], acc);          \
        }                                                                       \
    }

__global__ __launch_bounds__(256) void f1_k(const int* __restrict__ cnt,
                                            const int* __restrict__ bkt,
                                            const float* __restrict__ as1,
                                            const float* __restrict__ ad1,
                                            const uchar_t* __restrict__ h1f,
                                            const float* __restrict__ b1p,
                                            const float* __restrict__ W2p,
                                            const float* __restrict__ a2sw,
                                            const float* __restrict__ a2dw,
                                            float* __restrict__ h2,
                                            float* __restrict__ a2s,
                                            float* __restrict__ a2d) {
    int wv = threadIdx.x >> 6;
    int lane = threadIdx.x & 63;
    int half = lane >> 5, l32 = lane & 31;
    int node = blockIdx.x * 8 + wv * 2 + half;
    int g = l32 >> 4;                     // edge-parity group within the half
    int koff = (l32 & 15) * 16;           // byte offset of this lane's 16 channels
    int h = (l32 & 15) >> 2;              // head of this lane's 16 channels
    int deg = min(cnt[node * CPAD], BSLOTS);
    const int* bp = bkt + (size_t)node * BSLOTS;
    float4 advec = *(const float4*)&ad1[(size_t)node * 4];
    __shared__ float wls[4][2][32][4];    // unnormalized exp weights per (edge, head)

    float acc[16] = {};
    float dn0, dn1, dn2, dn3;
    if (deg <= 32) {
        bool act = l32 < deg;
        int s_reg = node;                 // pad: self row (weight 0)
        if (act) s_reg = bp[l32];
        int sbase = half << 5;
        uint4 va[4], vb[4];
        float wa[4], wb[4];

        // issue the alpha gather + first TWO message batches before dependent math
        float4 av = *(const float4*)&as1[(size_t)s_reg * 4];
        PREL(0, va);
        if (deg > 8) PREL(8, vb);

        float e0 = act ? __expf(leaky(av.x + advec.x)) : 0.f;
        float e1 = act ? __expf(leaky(av.y + advec.y)) : 0.f;
        float e2 = act ? __expf(leaky(av.z + advec.z)) : 0.f;
        float e3 = act ? __expf(leaky(av.w + advec.w)) : 0.f;
        *(float4*)&wls[wv][half][l32][0] = make_float4(e0, e1, e2, e3);
        dn0 = e0; dn1 = e1; dn2 = e2; dn3 = e3;
        #pragma unroll
        for (int off = 16; off; off >>= 1) {     // 32-lane reduce, stays in half
            dn0 += __shfl_xor(dn0, off, 64);
            dn1 += __shfl_xor(dn1, off, 64);
            dn2 += __shfl_xor(dn2, off, 64);
            dn3 += __shfl_xor(dn3, off, 64);
        }
        PREW(0, wa);
        if (deg > 8) PREW(8, wb);

        CONS(0, va, wa);
        if (deg > 8) {
            if (deg > 16) { PREL(16, va); PREW(16, wa); }
            CONS(8, vb, wb);
            if (deg > 16) {
                if (deg > 24) { PREL(24, vb); PREW(24, wb); }
                CONS(16, va, wa);
                if (deg > 24) CONS(24, vb, wb);
            }
        }
    } else {
        // fallback deg 33..96 — rare (P ~ 5e-4 per node)
        dn0 = dn1 = dn2 = dn3 = 0.f;
        for (int j = l32; j < deg; j += 32) {
            int s = bp[j];
            float4 av = *(const float4*)&as1[(size_t)s * 4];
            dn0 += __expf(leaky(av.x + advec.x));
            dn1 += __expf(leaky(av.y + advec.y));
            dn2 += __expf(leaky(av.z + advec.z));
            dn3 += __expf(leaky(av.w + advec.w));
        }
        #pragma unroll
        for (int off = 16; off; off >>= 1) {
            dn0 += __shfl_xor(dn0, off, 64);
            dn1 += __shfl_xor(dn1, off, 64);
            dn2 += __shfl_xor(dn2, off, 64);
            dn3 += __shfl_xor(dn3, off, 64);
        }
        float advh = hsel(advec, h);
        int cmax = deg - 1;
        for (int base = 0; base < deg; base += 2) {
            int e = base + g;
            int ce = min(e, cmax);
            int se = bp[ce];
            float ash = as1[(size_t)se * 4 + h];
            float w = (e < deg) ? __expf(leaky(ash + advh)) : 0.f;
            uint4 v = *(const uint4*)&h1f[(size_t)se * 256 + koff];
            dec16acc(v, w, acc);
        }
    }
    // merge edge-parity groups, then normalize
    float rdh = 1.f / hsel(make_float4(dn0, dn1, dn2, dn3), h);
    #pragma unroll
    for (int c = 0; c < 16; ++c) {
        acc[c] += __shfl_xor(acc[c], 16, 64);
        acc[c] *= rdh;
    }

    // relu(acc + b1p) -> GEMM2 (256 -> 8, permuted rows) -> alpha2 dots
    // 16 channels per lane over 16 lanes (both parity groups duplicate).
    int k0 = (l32 & 15) * 16;
    float xv[16];
    #pragma unroll
    for (int q4 = 0; q4 < 4; ++q4) {
        float4 bq = *(const float4*)&b1p[k0 + q4 * 4];
        xv[q4*4+0] = fmaxf(acc[q4*4+0] + bq.x, 0.f);
        xv[q4*4+1] = fmaxf(acc[q4*4+1] + bq.y, 0.f);
        xv[q4*4+2] = fmaxf(acc[q4*4+2] + bq.z, 0.f);
        xv[q4*4+3] = fmaxf(acc[q4*4+3] + bq.w, 0.f);
    }
    float p[8] = {};
    #pragma unroll
    for (int q = 0; q < 16; ++q) {
        const float4* w2p = (const float4*)&W2p[(size_t)(k0 + q) * 8];
        float4 wa2 = w2p[0], wb2 = w2p[1];
        p[0] += xv[q] * wa2.x; p[1] += xv[q] * wa2.y; p[2] += xv[q] * wa2.z; p[3] += xv[q] * wa2.w;
        p[4] += xv[q] * wb2.x; p[5] += xv[q] * wb2.y; p[6] += xv[q] * wb2.z; p[7] += xv[q] * wb2.w;
    }
    #pragma unroll
    for (int off = 8; off; off >>= 1)     // reduce over the 16 channel-lanes only
        #pragma unroll
        for (int c = 0; c < 8; ++c) p[c] += __shfl_xor(p[c], off, 64);
    if (l32 == 0) {
        *(float4*)&h2[(size_t)node * 8]     = make_float4(p[0], p[1], p[2], p[3]);
        *(float4*)&h2[(size_t)node * 8 + 4] = make_float4(p[4], p[5], p[6], p[7]);
        float vs = 0.f, vd = 0.f;
        #pragma unroll
        for (int c = 0; c < 8; ++c) { vs += p[c] * a2sw[c]; vd += p[c] * a2dw[c]; }
        a2s[node] = vs; a2d[node] = vd;
    }
}

// ------- fused layer-2: TWO nodes per wave, 8-deep dual-chain gather + log_softmax -------
// (r5 version — measured best)
__global__ __launch_bounds__(256) void f2_k(const int* __restrict__ cnt,
                                            const int* __restrict__ bkt,
                                            const float* __restrict__ a2s,
                                            const float* __restrict__ a2d,
                                            const float* __restrict__ h2,
                                            const float* __restrict__ b2,
                                            float* __restrict__ out) {
    int wv = threadIdx.x >> 6;
    int lane = threadIdx.x & 63;
    int half = lane >> 5, l32 = lane & 31;
    int node = blockIdx.x * 8 + wv * 2 + half;
    int deg = min(cnt[node * CPAD], BSLOTS);
    const int* bp = bkt + (size_t)node * BSLOTS;
    float adv = a2d[node];

    float acc_a = 0.f, acc_b = 0.f;
    float den;
    int c = l32 & 7, eg = l32 >> 3;        // 8 edges per pass (2 chains x 4), 8 ch each
    if (deg <= 32) {
        bool act = l32 < deg;
        int s_reg = node;
        if (act) s_reg = bp[l32];
        float ex = act ? __expf(leaky(a2s[s_reg] + adv)) : 0.f;
        den = ex;
        #pragma unroll
        for (int off = 16; off; off >>= 1) den += __shfl_xor(den, off, 64);
        int nb = (deg + 7) & ~7;
        int sbase = half << 5;
        for (int base = 0; base < nb; base += 8) {
            int e1 = base + eg, e2 = base + 4 + eg;
            int se1 = __shfl(s_reg, sbase + e1, 64);
            float w1 = __shfl(ex,    sbase + e1, 64);
            int se2 = __shfl(s_reg, sbase + e2, 64);
            float w2 = __shfl(ex,    sbase + e2, 64);
            acc_a += w1 * h2[(size_t)se1 * 8 + c];
            acc_b += w2 * h2[(size_t)se2 * 8 + c];
        }
    } else {
        den = 0.f;
        for (int j = l32; j < deg; j += 32) {
            int s = bp[j];
            den += __expf(leaky(a2s[s] + adv));
        }
        #pragma unroll
        for (int off = 16; off; off >>= 1) den += __shfl_xor(den, off, 64);
        int cmax = deg - 1;
        for (int base = 0; base < deg; base += 4) {
            int e = base + eg, ce = min(e, cmax);
            int se = bp[ce];
            float w = (e < deg) ? __expf(leaky(a2s[se] + adv)) : 0.f;
            acc_a += w * h2[(size_t)se * 8 + c];
        }
    }
    float acc = acc_a + acc_b;
    acc += __shfl_xor(acc, 8, 64);
    acc += __shfl_xor(acc, 16, 64);
    acc /= den;

    float v = acc + b2[c];
    float mx = v;
    #pragma unroll
    for (int off = 1; off < 8; off <<= 1) mx = fmaxf(mx, __shfl_xor(mx, off, 64));
    float ex2 = __expf(v - mx);
    float ss = ex2;
    #pragma unroll
    for (int off = 1; off < 8; off <<= 1) ss += __shfl_xor(ss, off, 64);
    if (l32 < 8) out[(size_t)node * 8 + c] = v - (mx + __logf(ss));
}

extern "C" void kernel_launch(void* const* d_in, const int* in_sizes, int n_in,
                              void* d_out, int out_size, void* d_ws, size_t ws_size,
                              hipStream_t stream) {
    const float* x    = (const float*)d_in[0];
    const int*   ei   = (const int*)  d_in[1];
    const float* W1   = (const float*)d_in[2];
    const float* a1sw = (const float*)d_in[3];
    const float* a1dw = (const float*)d_in[4];
    const float* b1   = (const float*)d_in[5];
    const float* W2   = (const float*)d_in[6];
    const float* a2sw = (const float*)d_in[7];
    const float* a2dw = (const float*)d_in[8];
    const float* b2   = (const float*)d_in[9];
    float* out = (float*)d_out;

    uchar_t* h1f = (uchar_t*)d_ws;            // 12,800,000 B (fp8 e4m3, permuted channels)
    ushort_t* W1c = (ushort_t*)(h1f + 12800000);  //  65,536 bf16 (chunked W1)
    float* as1  = (float*)(W1c + 65536);      //    200,000 f (16B-aligned)
    float* ad1  = as1 + 200000;               //    200,000 f
    float* h2   = ad1 + 200000;               //    400,000 f
    float* a2s  = h2  + 400000;               //     50,000 f
    float* a2d  = a2s + 50000;                //     50,000 f
    float* b1p  = a2d + 50000;                //        256 f (permuted b1)
    float* W2p  = b1p + 256;                  //      2,048 f (permuted W2)
    int*   cnt  = (int*)(W2p + 2048);         //    800,000 i (64B-strided counters)
    int*   bkt  = cnt + NNODES * CPAD;        //  4,800,000 i (50000 * 96 slots)

    // ---- prep: W1 conv + b1/W2 permute + padded cnt zero ----
    prep_k<<<257, 256, 0, stream>>>(W1, W1c, b1, W2, b1p, W2p, cnt);

    // ---- gemm1 (MFMA bf16, fused alpha1, permuted fp8 store) || bucketed CSR ----
    gb_k<<<NTILE + BBLK, 256, 0, stream>>>(x, W1c, a1sw, a1dw, h1f, as1, ad1,
                                           ei, cnt, bkt);

    // ---- fused layer-1 gather (fp8, quarter-group uint4 loads) + GEMM2 + alpha2 ----
    f1_k<<<NNODES / 8, 256, 0, stream>>>(cnt, bkt, as1, ad1, h1f, b1p, W2p,
                                         a2sw, a2dw, h2, a2s, a2d);

    // ---- fused layer-2 gather + log_softmax (2 nodes per wave, 8-deep) ----
    f2_k<<<NNODES / 8, 256, 0, stream>>>(cnt, bkt, a2s, a2d, h2, b2, out);
}

// Round 8
// 254.142 us; speedup vs baseline: 1.1996x; 1.1996x over previous
//
#include <hip/hip_runtime.h>
#include <math.h>

#define NNODES 50000
#define NEDGES 800000
#define ETOT   850000      // NEDGES + NNODES self-loops
#define SLOPE  0.2f
#define BSLOTS 96          // bucket slots/node; P(Poisson(17) deg >= 96) < 1e-40
#define CPAD   16          // cnt stride: one counter per 64B line (atomic false-sharing fix)
#define NTILE  782         // ceil(NNODES/64) gemm1 tiles
#define BBLK   518         // bucket blocks appended after the gemm tiles

typedef unsigned short ushort_t;
typedef unsigned int   uint_t;
typedef unsigned char  uchar_t;
typedef __attribute__((ext_vector_type(8))) __bf16 bf16x8;
typedef __attribute__((ext_vector_type(4))) float  floatx4;
typedef __attribute__((ext_vector_type(2))) float  floatx2;

// gfx950 has HW OCP-e4m3 <-> f32 converters (v_cvt_pk_f32_fp8 / v_cvt_pk_fp8_f32).
#if defined(__has_builtin)
#if __has_builtin(__builtin_amdgcn_cvt_pk_f32_fp8) && __has_builtin(__builtin_amdgcn_cvt_pk_fp8_f32)
#define HWFP8 1
#endif
#endif

__device__ __forceinline__ float leaky(float v) { return fmaxf(v, SLOPE * v); }  // slope<1

__device__ __forceinline__ ushort_t f2bf(float f) {       // fp32 -> bf16 RNE
    uint_t u = __float_as_uint(f);
    uint_t r = (u + 0x7fffu + ((u >> 16) & 1u)) >> 16;
    return (ushort_t)r;
}

// ---- software fallback fp8 codec (only compiled if HW builtins are absent) ----
__device__ __forceinline__ uint_t f2fp8_sw(float f) {
    uint_t u = __float_as_uint(f);
    uint_t s = (u >> 24) & 0x80u;
    u &= 0x7fffffffu;
    u = u + 0x7ffffu + ((u >> 20) & 1u);      // RNE to 3 mantissa bits
    int e8 = (int)(u >> 23) - 120;            // fp32 bias 127 -> e4m3 bias 7
    uint_t m3 = (u >> 20) & 7u;
    if (e8 <= 0) return s;                    // flush denormal / zero
    if (e8 >= 16) return s | 0x7eu;           // saturate to 448
    return s | ((uint_t)e8 << 3) | m3;
}
__device__ __forceinline__ float fp8tof_sw(uint_t b) {
    uint_t t = (b & 0x7fu) << 4;
    uint_t r = ((b & 0x80u) << 8) | (t + 0x3C00u);
    return (t >= 0x80u) ? __uint_as_float(r << 16) : 0.f;
}

// pack 4 f32 -> 4 e4m3 bytes (byte c = channel c)
__device__ __forceinline__ uint_t pk4fp8(float a, float b, float c, float d) {
#ifdef HWFP8
    int pk = 0;
    pk = __builtin_amdgcn_cvt_pk_fp8_f32(a, b, pk, false);   // bytes 0,1
    pk = __builtin_amdgcn_cvt_pk_fp8_f32(c, d, pk, true);    // bytes 2,3
    return (uint_t)pk;
#else
    return f2fp8_sw(a) | (f2fp8_sw(b) << 8) | (f2fp8_sw(c) << 16) | (f2fp8_sw(d) << 24);
#endif
}

// decode 8 e4m3 bytes (uint2) and accumulate: acc[c] += w * val[c]
__device__ __forceinline__ void dec8acc(uint2 v, float w, float* acc) {
#ifdef HWFP8
    floatx2 f0 = __builtin_amdgcn_cvt_pk_f32_fp8((int)v.x, false);
    floatx2 f1 = __builtin_amdgcn_cvt_pk_f32_fp8((int)v.x, true);
    floatx2 f2 = __builtin_amdgcn_cvt_pk_f32_fp8((int)v.y, false);
    floatx2 f3 = __builtin_amdgcn_cvt_pk_f32_fp8((int)v.y, true);
    acc[0] += w * f0.x; acc[1] += w * f0.y;
    acc[2] += w * f1.x; acc[3] += w * f1.y;
    acc[4] += w * f2.x; acc[5] += w * f2.y;
    acc[6] += w * f3.x; acc[7] += w * f3.y;
#else
    acc[0] += w * fp8tof_sw(v.x & 0xffu);
    acc[1] += w * fp8tof_sw((v.x >> 8) & 0xffu);
    acc[2] += w * fp8tof_sw((v.x >> 16) & 0xffu);
    acc[3] += w * fp8tof_sw(v.x >> 24);
    acc[4] += w * fp8tof_sw(v.y & 0xffu);
    acc[5] += w * fp8tof_sw((v.y >> 8) & 0xffu);
    acc[6] += w * fp8tof_sw((v.y >> 16) & 0xffu);
    acc[7] += w * fp8tof_sw(v.y >> 24);
#endif
}

__device__ __forceinline__ float hsel(float4 v, int h) {  // v[h]
    float t0 = (h & 1) ? v.y : v.x;
    float t1 = (h & 1) ? v.w : v.z;
    return (h & 2) ? t1 : t0;
}

__device__ __forceinline__ int esrc(const int* ei, int e) { return e < NEDGES ? ei[e]          : e - NEDGES; }
__device__ __forceinline__ int edst(const int* ei, int e) { return e < NEDGES ? ei[NEDGES + e] : e - NEDGES; }

// ------- prep: W1->bf16 chunk conv + b1/W2 permute + padded-cnt zero (one kernel) -------
__global__ void prep_k(const float* __restrict__ W1, ushort_t* __restrict__ W1c,
                       const float* __restrict__ b1, const float* __restrict__ W2,
                       float* __restrict__ b1p, float* __restrict__ W2p,
                       int* __restrict__ cnt) {
    int bid = blockIdx.x, tid = threadIdx.x;
    int gtid = bid * 256 + tid;
    if (bid < 256) {                          // W1 row-major [k][n] -> W1c[kc][n][kk]
        int k = gtid >> 8, n = gtid & 255;
        W1c[(k >> 5) * 8192 + n * 32 + (k & 31)] = f2bf(W1[gtid]);
    } else if (bid == 256) {                  // permuted channel: head*64 + c15*4 + tn
        int chp = tid;
        int q = chp & 63, cc = q >> 2, t = q & 3;
        int ch = (chp & 192) | (t * 16 + cc);
        b1p[chp] = b1[ch];
        #pragma unroll
        for (int j = 0; j < 8; ++j) W2p[chp * 8 + j] = W2[ch * 8 + j];
    }
    for (int i = gtid; i < NNODES * CPAD; i += 257 * 256) cnt[i] = 0;
}

// ------- fused gemm1 || bucket: blocks [0,NTILE) do MFMA tiles, rest bucket edges -------
// B-tile is NOT staged through LDS anymore: W1c is 64 KB, L2-resident after the first
// blocks, and the fragment address map (c15*64B + quad*16B) is a perfectly-coalesced
// 1 KB wave-load. A-tile stays in LDS (4-wave reuse) but the next-kc A rows are
// prefetched into registers during the MFMA phase, so global latency is not exposed
// between the two barriers.
__global__ __launch_bounds__(256) void gb_k(const float* __restrict__ X,
                                            const ushort_t* __restrict__ W1c,
                                            const float* __restrict__ att_s,
                                            const float* __restrict__ att_d,
                                            uchar_t* __restrict__ h1f,
                                            float* __restrict__ as1,
                                            float* __restrict__ ad1,
                                            const int* __restrict__ ei,
                                            int* __restrict__ cnt,
                                            int* __restrict__ bkt) {
    __shared__ ushort_t Als[64 * 40];     // A tile [64][32] bf16, row pad to 40
    int tid = threadIdx.x;

    if (blockIdx.x >= NTILE) {
        // -------- bucketed CSR over the edge list (+ implicit self-loops) --------
        for (int e = (blockIdx.x - NTILE) * 256 + tid; e < ETOT; e += BBLK * 256) {
            int d = edst(ei, e), s = esrc(ei, e);
            int pos = atomicAdd(&cnt[d * CPAD], 1);
            if (pos < BSLOTS) bkt[d * BSLOTS + pos] = s;
        }
        return;
    }

    // -------- one 64-row gemm tile --------
    int row0 = blockIdx.x * 64;
    int wv = tid >> 6, lane = tid & 63, c15 = lane & 15, quad = lane >> 4;
    floatx4 acc[4][4] = {};               // [tm][tn]

    int r = tid >> 3, c4 = tid & 7;
    int rowA = row0 + r, rowB = row0 + r + 32;
    float4 pa0 = make_float4(0.f, 0.f, 0.f, 0.f);
    float4 pa1 = make_float4(0.f, 0.f, 0.f, 0.f);
    if (rowA < NNODES) pa0 = *(const float4*)&X[(size_t)rowA * 256 + c4 * 4];
    if (rowB < NNODES) pa1 = *(const float4*)&X[(size_t)rowB * 256 + c4 * 4];

    for (int kc = 0; kc < 8; ++kc) {
        if (kc) __syncthreads();          // WAR: prev iteration's Als reads complete
        {
            uint2 pk;
            pk.x = (uint_t)f2bf(pa0.x) | ((uint_t)f2bf(pa0.y) << 16);
            pk.y = (uint_t)f2bf(pa0.z) | ((uint_t)f2bf(pa0.w) << 16);
            *(uint2*)&Als[r * 40 + c4 * 4] = pk;
            pk.x = (uint_t)f2bf(pa1.x) | ((uint_t)f2bf(pa1.y) << 16);
            pk.y = (uint_t)f2bf(pa1.z) | ((uint_t)f2bf(pa1.w) << 16);
            *(uint2*)&Als[(r + 32) * 40 + c4 * 4] = pk;
        }
        __syncthreads();
        // prefetch next-kc A rows (consumed next iteration; overlaps MFMA below)
        if (kc < 7) {
            pa0 = make_float4(0.f, 0.f, 0.f, 0.f);
            pa1 = make_float4(0.f, 0.f, 0.f, 0.f);
            if (rowA < NNODES) pa0 = *(const float4*)&X[(size_t)rowA * 256 + (kc + 1) * 32 + c4 * 4];
            if (rowB < NNODES) pa1 = *(const float4*)&X[(size_t)rowB * 256 + (kc + 1) * 32 + c4 * 4];
        }
        uint4 af[4], bfr[4];
        #pragma unroll
        for (int t = 0; t < 4; ++t)
            af[t] = *(const uint4*)&Als[(t * 16 + c15) * 40 + quad * 8];
        #pragma unroll
        for (int t = 0; t < 4; ++t)
            bfr[t] = *(const uint4*)&W1c[kc * 8192 + (wv * 64 + t * 16 + c15) * 32 + quad * 8];
        #pragma unroll
        for (int tm = 0; tm < 4; ++tm)
            #pragma unroll
            for (int tn = 0; tn < 4; ++tn)
                acc[tm][tn] = __builtin_amdgcn_mfma_f32_16x16x32_bf16(
                    __builtin_bit_cast(bf16x8, af[tm]),
                    __builtin_bit_cast(bf16x8, bfr[tn]),
                    acc[tm][tn], 0, 0, 0);
    }

    // alpha partials on ORIGINAL channel indexing (heads unchanged by the permute)
    // NOTE: computed from fp32 acc BEFORE fp8 quantization -> logits stay accurate
    float asv[4], adv[4];
    #pragma unroll
    for (int tn = 0; tn < 4; ++tn) {
        asv[tn] = att_s[wv * 64 + tn * 16 + c15];
        adv[tn] = att_d[wv * 64 + tn * 16 + c15];
    }
    float ps[4][4], pd[4][4];
    #pragma unroll
    for (int tm = 0; tm < 4; ++tm)
        #pragma unroll
        for (int r2 = 0; r2 < 4; ++r2) {
            float vs = 0.f, vd = 0.f;
            #pragma unroll
            for (int tn = 0; tn < 4; ++tn) {
                float a = acc[tm][tn][r2];
                vs += a * asv[tn]; vd += a * adv[tn];
            }
            ps[tm][r2] = vs; pd[tm][r2] = vd;
        }
    // permuted fp8 stores: h1f[row][wv*64 + c15*4 + tn] -> one uint (4 e4m3) per (tm,r)
    #pragma unroll
    for (int tm = 0; tm < 4; ++tm) {
        #pragma unroll
        for (int r2 = 0; r2 < 4; ++r2) {
            int row = row0 + tm * 16 + quad * 4 + r2;
            if (row < NNODES) {
                uint_t pk = pk4fp8(acc[tm][0][r2], acc[tm][1][r2],
                                   acc[tm][2][r2], acc[tm][3][r2]);
                *(uint_t*)&h1f[(size_t)row * 256 + wv * 64 + c15 * 4] = pk;
            }
        }
    }
    #pragma unroll
    for (int off = 1; off < 16; off <<= 1)
        #pragma unroll
        for (int tm = 0; tm < 4; ++tm)
            #pragma unroll
            for (int r2 = 0; r2 < 4; ++r2) {
                ps[tm][r2] += __shfl_xor(ps[tm][r2], off, 64);
                pd[tm][r2] += __shfl_xor(pd[tm][r2], off, 64);
            }
    if (c15 == 0) {
        #pragma unroll
        for (int tm = 0; tm < 4; ++tm)
            #pragma unroll
            for (int r2 = 0; r2 < 4; ++r2) {
                int row = row0 + tm * 16 + quad * 4 + r2;
                if (row < NNODES) {
                    as1[row * 4 + wv] = ps[tm][r2];
                    ad1[row * 4 + wv] = pd[tm][r2];
                }
            }
    }
}

// ------- fused layer-1: TWO nodes per wave, 8-deep gather, fp8 messages (r5: measured best) -------
#define PREL(BASE, VV)                                                          \
    {                                                                           \
        _Pragma("unroll")                                                       \
        for (int u = 0; u < 8; ++u) {                                           \
            int e = (BASE) + u;                                                 \
            int se = __shfl(s_reg, sbase + e, 64);                              \
            if (e < deg)                                                        \
                VV[u] = *(const uint2*)&h1f[(size_t)se * 256 + l32 * 8];        \
        }                                                                       \
    }
#define PREW(BASE, WW)                                                          \
    {                                                                           \
        _Pragma("unroll")                                                       \
        for (int u = 0; u < 8; ++u) WW[u] = wls[wv][half][(BASE) + u][h];       \
    }
#define CONS(BASE, VV, WW)                                                      \
    {                                                                           \
        _Pragma("unroll")                                                       \
        for (int u = 0; u < 8; ++u) {                                           \
            if ((BASE) + u < deg) dec8acc(VV[u], WW[u], acc);                   \
        }                                                                       \
    }

__global__ __launch_bounds__(256) void f1_k(const int* __restrict__ cnt,
                                            const int* __restrict__ bkt,
                                            const float* __restrict__ as1,
                                            const float* __restrict__ ad1,
                                            const uchar_t* __restrict__ h1f,
                                            const float* __restrict__ b1p,
                                            const float* __restrict__ W2p,
                                            const float* __restrict__ a2sw,
                                            const float* __restrict__ a2dw,
                                            float* __restrict__ h2,
                                            float* __restrict__ a2s,
                                            float* __restrict__ a2d) {
    int wv = threadIdx.x >> 6;
    int lane = threadIdx.x & 63;
    int half = lane >> 5, l32 = lane & 31;
    int node = blockIdx.x * 8 + wv * 2 + half;
    int h = l32 >> 3;                     // head of this lane's 8 channels
    int deg = min(cnt[node * CPAD], BSLOTS);
    const int* bp = bkt + (size_t)node * BSLOTS;
    float4 advec = *(const float4*)&ad1[(size_t)node * 4];
    __shared__ float wls[4][2][32][4];    // unnormalized exp weights per (edge, head)

    float acc[8] = {};
    float dn0, dn1, dn2, dn3;
    if (deg <= 32) {
        bool act = l32 < deg;
        int s_reg = node;                 // pad: self row (weight 0)
        if (act) s_reg = bp[l32];
        int sbase = half << 5;
        uint2 va[8], vb[8];
        float wa[8], wb[8];

        // issue the alpha gather + first TWO message batches before dependent math
        float4 av = *(const float4*)&as1[(size_t)s_reg * 4];
        PREL(0, va);
        if (deg > 8) PREL(8, vb);

        float e0 = act ? __expf(leaky(av.x + advec.x)) : 0.f;
        float e1 = act ? __expf(leaky(av.y + advec.y)) : 0.f;
        float e2 = act ? __expf(leaky(av.z + advec.z)) : 0.f;
        float e3 = act ? __expf(leaky(av.w + advec.w)) : 0.f;
        *(float4*)&wls[wv][half][l32][0] = make_float4(e0, e1, e2, e3);
        dn0 = e0; dn1 = e1; dn2 = e2; dn3 = e3;
        #pragma unroll
        for (int off = 16; off; off >>= 1) {     // 32-lane reduce, stays in half
            dn0 += __shfl_xor(dn0, off, 64);
            dn1 += __shfl_xor(dn1, off, 64);
            dn2 += __shfl_xor(dn2, off, 64);
            dn3 += __shfl_xor(dn3, off, 64);
        }
        PREW(0, wa);
        if (deg > 8) PREW(8, wb);

        CONS(0, va, wa);
        if (deg > 8) {
            if (deg > 16) { PREL(16, va); PREW(16, wa); }
            CONS(8, vb, wb);
            if (deg > 16) {
                if (deg > 24) { PREL(24, vb); PREW(24, wb); }
                CONS(16, va, wa);
                if (deg > 24) CONS(24, vb, wb);
            }
        }
    } else {
        // fallback deg 33..96 — rare (P ~ 5e-4 per node)
        dn0 = dn1 = dn2 = dn3 = 0.f;
        for (int j = l32; j < deg; j += 32) {
            int s = bp[j];
            float4 av = *(const float4*)&as1[(size_t)s * 4];
            dn0 += __expf(leaky(av.x + advec.x));
            dn1 += __expf(leaky(av.y + advec.y));
            dn2 += __expf(leaky(av.z + advec.z));
            dn3 += __expf(leaky(av.w + advec.w));
        }
        #pragma unroll
        for (int off = 16; off; off >>= 1) {
            dn0 += __shfl_xor(dn0, off, 64);
            dn1 += __shfl_xor(dn1, off, 64);
            dn2 += __shfl_xor(dn2, off, 64);
            dn3 += __shfl_xor(dn3, off, 64);
        }
        float advh = hsel(advec, h);
        int cmax = deg - 1;
        for (int base = 0; base < deg; base += 8) {
            #pragma unroll
            for (int u = 0; u < 8; ++u) {
                int e = base + u;
                int ce = min(e, cmax);
                int se = bp[ce];
                float ash = as1[(size_t)se * 4 + h];
                float w = (e < deg) ? __expf(leaky(ash + advh)) : 0.f;
                uint2 v = *(const uint2*)&h1f[(size_t)se * 256 + l32 * 8];
                dec8acc(v, w, acc);
            }
        }
    }
    float rdh = 1.f / hsel(make_float4(dn0, dn1, dn2, dn3), h);
    #pragma unroll
    for (int c = 0; c < 8; ++c) acc[c] *= rdh;

    // relu(acc + b1p) -> GEMM2 (256 -> 8, permuted rows) -> alpha2 dots
    int k0 = l32 * 8;
    float4 ba = *(const float4*)&b1p[k0];
    float4 bb = *(const float4*)&b1p[k0 + 4];
    float xv[8];
    xv[0] = fmaxf(acc[0] + ba.x, 0.f); xv[1] = fmaxf(acc[1] + ba.y, 0.f);
    xv[2] = fmaxf(acc[2] + ba.z, 0.f); xv[3] = fmaxf(acc[3] + ba.w, 0.f);
    xv[4] = fmaxf(acc[4] + bb.x, 0.f); xv[5] = fmaxf(acc[5] + bb.y, 0.f);
    xv[6] = fmaxf(acc[6] + bb.z, 0.f); xv[7] = fmaxf(acc[7] + bb.w, 0.f);
    float p[8] = {};
    #pragma unroll
    for (int q = 0; q < 8; ++q) {
        const float4* w2p = (const float4*)&W2p[(size_t)(k0 + q) * 8];
        float4 wa2 = w2p[0], wb2 = w2p[1];
        p[0] += xv[q] * wa2.x; p[1] += xv[q] * wa2.y; p[2] += xv[q] * wa2.z; p[3] += xv[q] * wa2.w;
        p[4] += xv[q] * wb2.x; p[5] += xv[q] * wb2.y; p[6] += xv[q] * wb2.z; p[7] += xv[q] * wb2.w;
    }
    #pragma unroll
    for (int off = 16; off; off >>= 1)
        #pragma unroll
        for (int c = 0; c < 8; ++c) p[c] += __shfl_xor(p[c], off, 64);
    if (l32 == 0) {
        *(float4*)&h2[(size_t)node * 8]     = make_float4(p[0], p[1], p[2], p[3]);
        *(float4*)&h2[(size_t)node * 8 + 4] = make_float4(p[4], p[5], p[6], p[7]);
        float vs = 0.f, vd = 0.f;
        #pragma unroll
        for (int c = 0; c < 8; ++c) { vs += p[c] * a2sw[c]; vd += p[c] * a2dw[c]; }
        a2s[node] = vs; a2d[node] = vd;
    }
}

// ------- fused layer-2: TWO nodes per wave, 8-deep dual-chain gather + log_softmax -------
// (r5 version — measured best)
__global__ __launch_bounds__(256) void f2_k(const int* __restrict__ cnt,
                                            const int* __restrict__ bkt,
                                            const float* __restrict__ a2s,
                                            const float* __restrict__ a2d,
                                            const float* __restrict__ h2,
                                            const float* __restrict__ b2,
                                            float* __restrict__ out) {
    int wv = threadIdx.x >> 6;
    int lane = threadIdx.x & 63;
    int half = lane >> 5, l32 = lane & 31;
    int node = blockIdx.x * 8 + wv * 2 + half;
    int deg = min(cnt[node * CPAD], BSLOTS);
    const int* bp = bkt + (size_t)node * BSLOTS;
    float adv = a2d[node];

    float acc_a = 0.f, acc_b = 0.f;
    float den;
    int c = l32 & 7, eg = l32 >> 3;        // 8 edges per pass (2 chains x 4), 8 ch each
    if (deg <= 32) {
        bool act = l32 < deg;
        int s_reg = node;
        if (act) s_reg = bp[l32];
        float ex = act ? __expf(leaky(a2s[s_reg] + adv)) : 0.f;
        den = ex;
        #pragma unroll
        for (int off = 16; off; off >>= 1) den += __shfl_xor(den, off, 64);
        int nb = (deg + 7) & ~7;
        int sbase = half << 5;
        for (int base = 0; base < nb; base += 8) {
            int e1 = base + eg, e2 = base + 4 + eg;
            int se1 = __shfl(s_reg, sbase + e1, 64);
            float w1 = __shfl(ex,    sbase + e1, 64);
            int se2 = __shfl(s_reg, sbase + e2, 64);
            float w2 = __shfl(ex,    sbase + e2, 64);
            acc_a += w1 * h2[(size_t)se1 * 8 + c];
            acc_b += w2 * h2[(size_t)se2 * 8 + c];
        }
    } else {
        den = 0.f;
        for (int j = l32; j < deg; j += 32) {
            int s = bp[j];
            den += __expf(leaky(a2s[s] + adv));
        }
        #pragma unroll
        for (int off = 16; off; off >>= 1) den += __shfl_xor(den, off, 64);
        int cmax = deg - 1;
        for (int base = 0; base < deg; base += 4) {
            int e = base + eg, ce = min(e, cmax);
            int se = bp[ce];
            float w = (e < deg) ? __expf(leaky(a2s[se] + adv)) : 0.f;
            acc_a += w * h2[(size_t)se * 8 + c];
        }
    }
    float acc = acc_a + acc_b;
    acc += __shfl_xor(acc, 8, 64);
    acc += __shfl_xor(acc, 16, 64);
    acc /= den;

    float v = acc + b2[c];
    float mx = v;
    #pragma unroll
    for (int off = 1; off < 8; off <<= 1) mx = fmaxf(mx, __shfl_xor(mx, off, 64));
    float ex2 = __expf(v - mx);
    float ss = ex2;
    #pragma unroll
    for (int off = 1; off < 8; off <<= 1) ss += __shfl_xor(ss, off, 64);
    if (l32 < 8) out[(size_t)node * 8 + c] = v - (mx + __logf(ss));
}

extern "C" void kernel_launch(void* const* d_in, const int* in_sizes, int n_in,
                              void* d_out, int out_size, void* d_ws, size_t ws_size,
                              hipStream_t stream) {
    const float* x    = (const float*)d_in[0];
    const int*   ei   = (const int*)  d_in[1];
    const float* W1   = (const float*)d_in[2];
    const float* a1sw = (const float*)d_in[3];
    const float* a1dw = (const float*)d_in[4];
    const float* b1   = (const float*)d_in[5];
    const float* W2   = (const float*)d_in[6];
    const float* a2sw = (const float*)d_in[7];
    const float* a2dw = (const float*)d_in[8];
    const float* b2   = (const float*)d_in[9];
    float* out = (float*)d_out;

    uchar_t* h1f = (uchar_t*)d_ws;            // 12,800,000 B (fp8 e4m3, permuted channels)
    ushort_t* W1c = (ushort_t*)(h1f + 12800000);  //  65,536 bf16 (chunked W1)
    float* as1  = (float*)(W1c + 65536);      //    200,000 f (16B-aligned)
    float* ad1  = as1 + 200000;               //    200,000 f
    float* h2   = ad1 + 200000;               //    400,000 f
    float* a2s  = h2  + 400000;               //     50,000 f
    float* a2d  = a2s + 50000;                //     50,000 f
    float* b1p  = a2d + 50000;                //        256 f (permuted b1)
    float* W2p  = b1p + 256;                  //      2,048 f (permuted W2)
    int*   cnt  = (int*)(W2p + 2048);         //    800,000 i (64B-strided counters)
    int*   bkt  = cnt + NNODES * CPAD;        //  4,800,000 i (50000 * 96 slots)

    // ---- prep: W1 conv + b1/W2 permute + padded cnt zero ----
    prep_k<<<257, 256, 0, stream>>>(W1, W1c, b1, W2, b1p, W2p, cnt);

    // ---- gemm1 (MFMA bf16, B direct-from-L2, prefetched A) || bucketed CSR ----
    gb_k<<<NTILE + BBLK, 256, 0, stream>>>(x, W1c, a1sw, a1dw, h1f, as1, ad1,
                                           ei, cnt, bkt);

    // ---- fused layer-1 gather (fp8 messages, HW cvt) + GEMM2 + alpha2 ----
    f1_k<<<NNODES / 8, 256, 0, stream>>>(cnt, bkt, as1, ad1, h1f, b1p, W2p,
                                         a2sw, a2dw, h2, a2s, a2d);

    // ---- fused layer-2 gather + log_softmax (2 nodes per wave, 8-deep) ----
    f2_k<<<NNODES / 8, 256, 0, stream>>>(cnt, bkt, a2s, a2d, h2, b2, out);
}